// Round 12
// baseline (677.915 us; speedup 1.0000x reference)
//
#include <hip/hip_runtime.h>

typedef unsigned short u16;
typedef unsigned int   u32;
typedef __attribute__((ext_vector_type(8))) short short8;
typedef __attribute__((ext_vector_type(4))) float f32x4;

__device__ __forceinline__ float u2f(u32 u){
  union { u32 i; float f; } v; v.i = u << 16; return v.f;
}
__device__ __forceinline__ u16 f2bu(float f){
  union { float f; u32 i; } v; v.f = f;
  u32 i = v.i;
  i += 0x7fffu + ((i >> 16) & 1u);   // round-to-nearest-even
  return (u16)(i >> 16);
}
__device__ __forceinline__ float sigm(float x){ return 1.0f/(1.0f + expf(-x)); }
__device__ __forceinline__ float ldf(const void* p, size_t i, int bf){
  return bf ? u2f(((const u16*)p)[i]) : ((const float*)p)[i];
}
__device__ __forceinline__ float wsum(float v){
  #pragma unroll
  for (int off = 32; off > 0; off >>= 1) v += __shfl_xor(v, off, 64);
  return v;
}

// ---------------------------------------------------------------------------
// Kernel 0: dtype detector (bf16 vs f32 device buffers).
// ---------------------------------------------------------------------------
__global__ __launch_bounds__(64) void k_detect(const u32* __restrict__ nv,
                                               int* __restrict__ flag)
{
  int i = threadIdx.x;
  u32 w = nv[i];
  u32 e = (w >> 7) & 0xffu;
  bool sane = (e >= 100u && e <= 140u);
  unsigned long long m = __ballot(sane);
  if (i == 0) *flag = (__popcll(m) >= 40) ? 1 : 0;
}

// ---------------------------------------------------------------------------
// Kernel PR: merged prep — gcn_w pack (Wg [112][224]) + emb->bf16 Eb with
// ROW STRIDE 112 (224 B, 16B-aligned rows so gathers can use uint4).
// Range 0..25087: Wg; then 70001*28 4-elem units for Eb.
// ---------------------------------------------------------------------------
__global__ __launch_bounds__(256) void k_prep(
    const void* __restrict__ gcnw, u16* __restrict__ Wg,
    const void* __restrict__ emb, u16* __restrict__ Eb,
    const int* __restrict__ flag)
{
  const int bf = *flag;
  int idx = blockIdx.x*256 + threadIdx.x;
  if (idx < 25088){
    int r = idx / 224, k = idx - r*224;
    u16 v = 0;
    if (k < 200 && r < 100){
      size_t si = (size_t)r*200 + k;
      v = bf ? ((const u16*)gcnw)[si] : f2bu(((const float*)gcnw)[si]);
    }
    Wg[idx] = v;
    return;
  }
  int e4 = idx - 25088;
  if (e4 >= 70001*28) return;
  int row = e4 / 28, cq = e4 - row*28;
  int c0 = cq*4;
  union { u16 q[4]; uint2 d; } o;
  o.q[0] = 0; o.q[1] = 0; o.q[2] = 0; o.q[3] = 0;
  size_t sbase = (size_t)row*100;
  #pragma unroll
  for (int e = 0; e < 4; ++e){
    int c = c0 + e;
    if (c < 100)
      o.q[e] = bf ? ((const u16*)emb)[sbase+c] : f2bu(((const float*)emb)[sbase+c]);
  }
  *(uint2*)(Eb + (size_t)row*112 + c0) = o.d;
}

// ---------------------------------------------------------------------------
// helpers for the merged layer pack
// ---------------------------------------------------------------------------
__device__ __forceinline__ void packg_one(
    const void* __restrict__ src, u16* __restrict__ dst,
    int K, int Kp, int bf, int idx)   // idx in 4-elem units over 2*1920*Kp/4
{
  const int Kq = Kp >> 2;
  const int per = 1920*Kq;
  int z = idx / per, r = idx - z*per;
  int rp = r / Kq, cq = r - rp*Kq;
  int c0 = cq*4;
  int kblk = rp >> 6, rem = rp & 63, gate = rem >> 4, klo = rem & 15;
  int k = kblk*16 + klo;
  union { u16 q[4]; uint2 d; } o;
  o.q[0] = 0; o.q[1] = 0; o.q[2] = 0; o.q[3] = 0;
  if (k < 450){
    size_t base = ((size_t)z*1800 + (size_t)gate*450 + k)*K;
    #pragma unroll
    for (int e = 0; e < 4; ++e){
      int c = c0 + e;
      if (c < K)
        o.q[e] = bf ? ((const u16*)src)[base+c] : f2bu(((const float*)src)[base+c]);
    }
  }
  *(uint2*)(dst + (size_t)idx*4) = o.d;
}

// ---------------------------------------------------------------------------
// Kernel PL: merged per-layer pack: Wih->Wp (gate-interleaved), Whh->Whp,
// bias->Bp. Flat ranges: [0,n1) Wp units, [n1,n1+n2) Whp units, then Bp.
// ---------------------------------------------------------------------------
__global__ __launch_bounds__(256) void k_packL(
    const void* __restrict__ Wih, int Kih, int KpIh, u16* __restrict__ Wp,
    const void* __restrict__ Whh, u16* __restrict__ Whp,
    const void* __restrict__ bih, const void* __restrict__ bhh,
    float* __restrict__ Bp, const int* __restrict__ flag)
{
  const int bf = *flag;
  const int n1 = 2*1920*(KpIh >> 2);
  const int n2 = 2*1920*120;            // Whh: Kp=480 -> 120 units
  int idx = blockIdx.x*256 + threadIdx.x;
  if (idx < n1){ packg_one(Wih, Wp, Kih, KpIh, bf, idx); return; }
  idx -= n1;
  if (idx < n2){ packg_one(Whh, Whp, 450, 480, bf, idx); return; }
  idx -= n2;
  if (idx >= 2*1920) return;
  int z = idx / 1920, rp = idx - z*1920;
  int kblk = rp >> 6, rem = rp & 63, gate = rem >> 4, klo = rem & 15;
  int k = kblk*16 + klo;
  float v = 0.0f;
  if (k < 450){
    size_t si = (size_t)z*1800 + (size_t)gate*450 + k;
    v = ldf(bih, si, bf) + ldf(bhh, si, bf);
  }
  Bp[idx] = v;
}

// ---------------------------------------------------------------------------
// Kernel 1: neighbor encoder. Gathers read Eb (stride 112) as 16B uint4
// slots (4 threads/row/kc; k==96 slot straddles c1/c2 and splits into two
// uint2). Register prefetch; accumulator shfl tail; self-padding X0bf.
// ---------------------------------------------------------------------------
__global__ __launch_bounds__(512, 4) void k_gcn(
    const int* __restrict__ left, const int* __restrict__ right,
    const void* __restrict__ emb, const u16* __restrict__ Eb,
    const u16* __restrict__ Wg,
    const void* __restrict__ gcnwb, const void* __restrict__ gcnb,
    const void* __restrict__ attnw, const void* __restrict__ attnwb,
    const void* __restrict__ gatew, const void* __restrict__ gatewb,
    const void* __restrict__ gateb,
    const int* __restrict__ flag,
    u16* __restrict__ X0bf)
{
  __shared__ __align__(16) u16 As[208*40];    // 16640 B
  __shared__ __align__(16) u16 Bs[112*232];   // 51968 B
  __shared__ int c1_s[200], c2_s[200];
  __shared__ float logit_s[208];
  __shared__ float red_s[512];
  __shared__ float attnw_s[112], bias_s[112], gatew_s[112], oa_s[112];

  const int bf  = *flag;
  const int tid = threadIdx.x;
  const int n   = blockIdx.x;
  const int b   = n & 255;
  const int fs  = n >> 8;
  const int s   = fs & 1;
  const int f   = fs >> 1;
  const int* conn = (s == 0 ? left : right) + (size_t)(f*256 + b)*600;

  if (tid < 200){ c1_s[tid] = conn[tid*3+1]; c2_s[tid] = conn[tid*3+2]; }
  if (tid < 112){
    attnw_s[tid] = (tid < 100) ? ldf(attnw, tid, bf) : 0.0f;
    bias_s[tid]  = (tid < 100) ? (ldf(gcnwb, tid, bf) + ldf(gcnb, tid, bf)) : 0.0f;
    gatew_s[tid] = (tid < 100) ? ldf(gatew, tid, bf) : 0.0f;
    oa_s[tid] = 0.0f;
  }
  for (int g = tid; g < 112*28; g += 512){
    int r = g / 28, cc = g - r*28;
    *(short8*)(Bs + r*232 + cc*8) = *(const short8*)(Wg + (size_t)r*224 + cc*8);
  }
  // pad cols 200..223 of this row (done by the s==1 block)
  if (s == 1 && tid >= 100 && tid < 124)
    X0bf[((size_t)f*256 + b)*224 + 100 + tid] = 0;
  __syncthreads();

  const int wid  = tid >> 6, lane = tid & 63, ln = lane & 15, quad = lane >> 4;
  const int mt0 = (wid < 5) ? 2*wid : (10 + (wid - 5));
  const int nmt = (wid < 5) ? 2 : 1;

  // gather kc's A-slots: 832 uint4 slots (208 rows x 4), 2 per thread
  auto loadA = [&](int kc, uint4* pv){
    #pragma unroll
    for (int it = 0; it < 2; ++it){
      int g = tid + it*512;
      uint4 v; v.x = 0u; v.y = 0u; v.z = 0u; v.w = 0u;
      if (g < 832){
        int r = g >> 2, gi = g & 3, k = kc*32 + gi*8;
        if (r < 200 && k < 200){
          int c1 = c1_s[r], c2 = c2_s[r];
          if (k + 8 <= 100){
            v = *(const uint4*)(Eb + (size_t)c1*112 + k);
          } else if (k >= 100){
            v = *(const uint4*)(Eb + (size_t)c2*112 + (k-100));
          } else { // k == 96: c1[96..99] | c2[0..3]
            uint2 lo = *(const uint2*)(Eb + (size_t)c1*112 + 96);
            uint2 hi = *(const uint2*)(Eb + (size_t)c2*112);
            v.x = lo.x; v.y = lo.y; v.z = hi.x; v.w = hi.y;
          }
        }
      }
      pv[it] = v;
    }
  };

  f32x4 acc[2][7];
  #pragma unroll
  for (int i = 0; i < 2; ++i)
    #pragma unroll
    for (int j = 0; j < 7; ++j) acc[i][j] = (f32x4)0.0f;

  uint4 pv[2];
  loadA(0, pv);

  for (int kc = 0; kc < 7; ++kc){
    const int k0 = kc*32;
    #pragma unroll
    for (int it = 0; it < 2; ++it){
      int g = tid + it*512;
      if (g < 832){
        int r = g >> 2, gi = g & 3;
        *(uint4*)(As + r*40 + gi*8) = pv[it];
      }
    }
    __syncthreads();
    if (kc < 6) loadA(kc+1, pv);   // in flight under MFMA phase

    #pragma unroll
    for (int mi = 0; mi < 2; ++mi){
      if (mi < nmt){
        short8 afr = *(const short8*)(As + ((mt0+mi)*16 + ln)*40 + quad*8);
        #pragma unroll
        for (int nt = 0; nt < 7; ++nt){
          short8 bfr = *(const short8*)(Bs + (size_t)(nt*16 + ln)*232 + k0 + quad*8);
          acc[mi][nt] = __builtin_amdgcn_mfma_f32_16x16x32_bf16(afr, bfr, acc[mi][nt], 0, 0, 0);
        }
      }
    }
    __syncthreads();
  }

  const float awb = ldf(attnwb, 0, bf);
  #pragma unroll
  for (int mi = 0; mi < 2; ++mi){
    if (mi < nmt){
      #pragma unroll
      for (int rg = 0; rg < 4; ++rg){
        float p = 0.0f;
        #pragma unroll
        for (int nt = 0; nt < 7; ++nt){
          float x = acc[mi][nt][rg] + bias_s[nt*16 + ln];
          x = x > 0.0f ? x : 0.01f*x;
          p += x * attnw_s[nt*16 + ln];
        }
        p += __shfl_xor(p, 1, 64); p += __shfl_xor(p, 2, 64);
        p += __shfl_xor(p, 4, 64); p += __shfl_xor(p, 8, 64);
        int m = (mt0+mi)*16 + quad*4 + rg;
        if (ln == 0 && m < 200) logit_s[m] = p + awb;
      }
    }
  }
  __syncthreads();

  red_s[tid] = (tid < 200) ? logit_s[tid] : -3.0e38f;
  __syncthreads();
  for (int off = 256; off > 0; off >>= 1){
    if (tid < off) red_s[tid] = fmaxf(red_s[tid], red_s[tid+off]);
    __syncthreads();
  }
  float mx = red_s[0];
  __syncthreads();
  float ev = 0.0f;
  if (tid < 200) ev = expf(logit_s[tid] - mx);
  red_s[tid] = ev;
  __syncthreads();
  for (int off = 256; off > 0; off >>= 1){
    if (tid < off) red_s[tid] += red_s[tid+off];
    __syncthreads();
  }
  float S = red_s[0];
  __syncthreads();
  if (tid < 208) logit_s[tid] = (tid < 200) ? ev*(1.0f/S) : 0.0f;
  __syncthreads();

  float at[2][4];
  #pragma unroll
  for (int mi = 0; mi < 2; ++mi)
    #pragma unroll
    for (int rg = 0; rg < 4; ++rg)
      at[mi][rg] = (mi < nmt) ? logit_s[(mt0+mi)*16 + quad*4 + rg] : 0.0f;

  #pragma unroll
  for (int nt = 0; nt < 7; ++nt){
    float p = 0.0f;
    #pragma unroll
    for (int mi = 0; mi < 2; ++mi){
      if (mi < nmt){
        #pragma unroll
        for (int rg = 0; rg < 4; ++rg){
          float x = acc[mi][nt][rg] + bias_s[nt*16 + ln];
          x = x > 0.0f ? x : 0.01f*x;
          p += x * at[mi][rg];
        }
      }
    }
    p += __shfl_xor(p, 16, 64); p += __shfl_xor(p, 32, 64);
    if (quad == 0) atomicAdd(&oa_s[nt*16 + ln], p);
  }
  __syncthreads();

  red_s[tid] = (tid < 100) ? oa_s[tid]*gatew_s[tid] : 0.0f;
  __syncthreads();
  for (int off = 256; off > 0; off >>= 1){
    if (tid < off) red_s[tid] += red_s[tid+off];
    __syncthreads();
  }
  float gate = sigm(red_s[0] + ldf(gatewb, 0, bf) + ldf(gateb, 0, bf));
  if (tid < 100){
    int c0 = conn[0];
    float self = ldf(emb, (size_t)c0*100 + tid, bf);
    X0bf[((size_t)f*256 + b)*224 + s*100 + tid] = f2bu(oa_s[tid]*gate + self*(1.0f - gate));
  }
}

// ---------------------------------------------------------------------------
// Kernel M: MFMA GEMM (input projections only). out[z][row][col'] bf16 =
// A[row]·B'[col'] + Bp[z][col']. N=1920 exact (15x128 tiles), M mult of 128.
// ---------------------------------------------------------------------------
__global__ __launch_bounds__(256) void k_mgemm(
    const u16* __restrict__ A, int lda, size_t Astride,
    const u16* __restrict__ B, int ldb, size_t Bstride,
    const float* __restrict__ bsum,
    u16* __restrict__ out, size_t Ostride,
    int N, int KC)
{
  __shared__ __align__(16) u16 As[128*40];
  __shared__ __align__(16) u16 Bs[128*40];
  const int tid = threadIdx.x;
  const int z  = blockIdx.z;
  const int nb = blockIdx.x, mb = blockIdx.y;
  const u16* Az = A + (size_t)z*Astride;
  const u16* Bz = B + (size_t)z*Bstride;

  const int wid = tid >> 6, lane = tid & 63, ln = lane & 15, quad = lane >> 4;
  const int wm = wid >> 1, wn = wid & 1;

  f32x4 acc[4][4];
  #pragma unroll
  for (int i = 0; i < 4; ++i)
    #pragma unroll
    for (int j = 0; j < 4; ++j) acc[i][j] = (f32x4)0.0f;

  const int srow = tid >> 1;
  const int koff = (tid & 1)*16;
  const int rowA = mb*128 + srow;
  const int rowB = nb*128 + srow;

  for (int kc = 0; kc < KC; ++kc){
    const int k0 = kc*32 + koff;
    const u16* ap = Az + (size_t)rowA*lda + k0;
    const u16* bp = Bz + (size_t)rowB*ldb + k0;
    short8 av0 = *(const short8*)(ap);
    short8 av1 = *(const short8*)(ap + 8);
    short8 bv0 = *(const short8*)(bp);
    short8 bv1 = *(const short8*)(bp + 8);
    *(short8*)(As + srow*40 + koff)     = av0;
    *(short8*)(As + srow*40 + koff + 8) = av1;
    *(short8*)(Bs + srow*40 + koff)     = bv0;
    *(short8*)(Bs + srow*40 + koff + 8) = bv1;
    __syncthreads();
    short8 af[4], bfr[4];
    #pragma unroll
    for (int i = 0; i < 4; ++i)
      af[i] = *(const short8*)(As + (wm*64 + i*16 + ln)*40 + quad*8);
    #pragma unroll
    for (int j = 0; j < 4; ++j)
      bfr[j] = *(const short8*)(Bs + (wn*64 + j*16 + ln)*40 + quad*8);
    #pragma unroll
    for (int i = 0; i < 4; ++i)
      #pragma unroll
      for (int j = 0; j < 4; ++j)
        acc[i][j] = __builtin_amdgcn_mfma_f32_16x16x32_bf16(af[i], bfr[j], acc[i][j], 0, 0, 0);
    __syncthreads();
  }

  #pragma unroll
  for (int j = 0; j < 4; ++j){
    int col = nb*128 + wn*64 + j*16 + ln;
    float bias = bsum ? bsum[(size_t)z*1920 + col] : 0.0f;
    #pragma unroll
    for (int i = 0; i < 4; ++i){
      #pragma unroll
      for (int rg = 0; rg < 4; ++rg){
        int row = mb*128 + wm*64 + i*16 + quad*4 + rg;
        out[(size_t)z*Ostride + (size_t)row*N + col] = f2bu(acc[i][j][rg] + bias);
      }
    }
  }
}

// ---------------------------------------------------------------------------
// Kernel H: fused hidden GEMM + LSTM cell, BARRIER-FREE / ZERO-LDS.
// Grid (30,8,2) = 480 one-wave blocks. Wave owns 32 rows x 64 cols' via TWO
// A-fragments sharing the 4 B-fragments: 6 loads / 8 MFMA per kc (was 5/4).
// `first` flag: s==0 skips the K-loop and c-read. Self-zeroing pads.
// col' = kb*64 + j*16 + ln  =>  gate j, k = kb*16 + ln (verified algebra).
// ---------------------------------------------------------------------------
__global__ __launch_bounds__(64) void k_hstep(
    const u16* __restrict__ Hin, const u16* __restrict__ Whp,
    const u16* __restrict__ Gb, float* __restrict__ HC,
    u16* __restrict__ Hout, u16* __restrict__ Ybf, float* __restrict__ Yf,
    float* __restrict__ HF, int s, int layer, int first)
{
  const int lane = threadIdx.x;
  const int ln = lane & 15, quad = lane >> 4;
  const int kb = blockIdx.x;      // 0..29: 64-col' group
  const int mb = blockIdx.y;      // 0..7 : 32-row group
  const int z  = blockIdx.z;

  f32x4 acc[2][4];
  #pragma unroll
  for (int i = 0; i < 2; ++i)
    #pragma unroll
    for (int j = 0; j < 4; ++j) acc[i][j] = (f32x4)0.0f;

  if (!first){
    const u16* Az = Hin + ((size_t)z*256 + mb*32)*480;
    const u16* Bz = Whp + (size_t)z*1920*480 + (size_t)kb*64*480;
    #pragma unroll
    for (int kc = 0; kc < 15; ++kc){
      const int k0 = kc*32 + quad*8;
      short8 a0 = *(const short8*)(Az + (size_t)ln*480 + k0);
      short8 a1 = *(const short8*)(Az + (size_t)(16 + ln)*480 + k0);
      #pragma unroll
      for (int j = 0; j < 4; ++j){
        short8 bfr = *(const short8*)(Bz + (size_t)(j*16 + ln)*480 + k0);
        acc[0][j] = __builtin_amdgcn_mfma_f32_16x16x32_bf16(a0, bfr, acc[0][j], 0, 0, 0);
        acc[1][j] = __builtin_amdgcn_mfma_f32_16x16x32_bf16(a1, bfr, acc[1][j], 0, 0, 0);
      }
    }
  }

  const int k = kb*16 + ln;
  const int t = z ? (4 - s) : s;
  if (k < 450){
    const u16* Gz = Gb + (size_t)z*2457600 + (size_t)t*256*1920;
    #pragma unroll
    for (int i = 0; i < 2; ++i){
      #pragma unroll
      for (int rg = 0; rg < 4; ++rg){
        int b = mb*32 + i*16 + quad*4 + rg;
        const u16* grow = Gz + (size_t)b*1920 + kb*64 + ln;
        float gi = acc[i][0][rg] + u2f(grow[0]);
        float gf = acc[i][1][rg] + u2f(grow[16]);
        float gg = acc[i][2][rg] + u2f(grow[32]);
        float go = acc[i][3][rg] + u2f(grow[48]);
        float* cp = HC + ((size_t)(2+z)*256 + b)*450 + k;
        float cprv = first ? 0.0f : *cp;
        float c = sigm(gf)*cprv + sigm(gi)*tanhf(gg);
        float h = sigm(go)*tanhf(c);
        *cp = c;
        Hout[((size_t)z*256 + b)*480 + k] = f2bu(h);
        if (Ybf) Ybf[((size_t)t*256 + b)*928 + z*450 + k] = f2bu(h);
        else     Yf [((size_t)t*256 + b)*900 + z*450 + k] = h;
        HF[((size_t)(layer*2+z)*256 + b)*450 + k] = h;
      }
    }
  } else {
    // pad maintenance: Hout cols [450,480); Y0bf cols [900,928) (z==1 only)
    #pragma unroll
    for (int i = 0; i < 2; ++i){
      #pragma unroll
      for (int rg = 0; rg < 4; ++rg){
        int b = mb*32 + i*16 + quad*4 + rg;
        Hout[((size_t)z*256 + b)*480 + k] = 0;
        if (z == 1 && Ybf && k < 478)
          Ybf[((size_t)t*256 + b)*928 + 450 + k] = 0;
      }
    }
  }
}

// ---------------------------------------------------------------------------
// Kernel 5: attention over timesteps + context (round-8 verified).
// ---------------------------------------------------------------------------
__global__ __launch_bounds__(256) void k_attn(
    const float* __restrict__ Y1, const float* __restrict__ HF,
    float* __restrict__ CTX)
{
  __shared__ float red2[40];
  __shared__ float aw[10];
  int b = blockIdx.x, tid = threadIdx.x;
  int wid = tid >> 6, lane = tid & 63;
  for (int p = 0; p < 10; ++p){
    int t = p >> 1, l = p & 1;
    float a = 0.0f;
    for (int h = tid; h < 900; h += 256)
      a += Y1[((size_t)t*256 + b)*900 + h] * HF[(size_t)b*1800 + h*2 + l];
    a = wsum(a);
    if (lane == 0) red2[p*4 + wid] = a;
  }
  __syncthreads();
  if (tid < 2){
    int l = tid;
    float sc[5];
    float mxv = -3.0e38f;
    for (int t = 0; t < 5; ++t){
      int p = t*2 + l;
      sc[t] = red2[p*4] + red2[p*4+1] + red2[p*4+2] + red2[p*4+3];
      mxv = fmaxf(mxv, sc[t]);
    }
    float e[5], sum = 0.0f;
    for (int t = 0; t < 5; ++t){ e[t] = expf(sc[t]-mxv); sum += e[t]; }
    for (int t = 0; t < 5; ++t) aw[t*2+l] = e[t]/sum;
  }
  __syncthreads();
  for (int h = tid; h < 900; h += 256){
    float v0 = 0.0f, v1 = 0.0f;
    for (int t = 0; t < 5; ++t){
      float y = Y1[((size_t)t*256 + b)*900 + h];
      v0 += y*aw[t*2+0]; v1 += y*aw[t*2+1];
    }
    CTX[(size_t)b*1800 + h*2 + 0] = v0;
    CTX[(size_t)b*1800 + h*2 + 1] = v1;
  }
}

// ---------------------------------------------------------------------------
// Kernel 2s: scalar GEMM (kept only for CTX @ out_w, C=100).
// ---------------------------------------------------------------------------
__global__ __launch_bounds__(256) void k_gemm(
    const float* __restrict__ A, const void* __restrict__ W, size_t wEl,
    const void* __restrict__ b1, const void* __restrict__ b2, size_t bEl,
    const int* __restrict__ flag,
    float* __restrict__ out, int K, int C)
{
  extern __shared__ float a_s[];
  const int bf = *flag;
  const int tid = threadIdx.x;
  const int r = blockIdx.y;
  const float* a = A + (size_t)r*K;
  for (int k = tid; k < K; k += 256) a_s[k] = a[k];
  __syncthreads();
  const int j = blockIdx.x*256 + tid;
  if (j >= C) return;
  float acc = 0.0f;
  if (b1) acc += ldf(b1, bEl + j, bf);
  if (b2) acc += ldf(b2, bEl + j, bf);
  if (bf){
    const u16* w = (const u16*)W + wEl + (size_t)j*K;
    for (int k = 0; k < K; k += 4){
      uint2 wv = *(const uint2*)(w + k);
      acc += a_s[k]   * u2f(wv.x & 0xffffu);
      acc += a_s[k+1] * u2f(wv.x >> 16);
      acc += a_s[k+2] * u2f(wv.y & 0xffffu);
      acc += a_s[k+3] * u2f(wv.y >> 16);
    }
  } else {
    const float* w = (const float*)W + wEl + (size_t)j*K;
    for (int k = 0; k < K; k += 4){
      float4 wv = *(const float4*)(w + k);
      acc += a_s[k]*wv.x + a_s[k+1]*wv.y + a_s[k+2]*wv.z + a_s[k+3]*wv.w;
    }
  }
  out[(size_t)r*C + j] = acc;
}

// ---------------------------------------------------------------------------
// Kernel 6: analytic meta-gradient. ONE WAVE per b (round-8 verified).
// ---------------------------------------------------------------------------
__global__ __launch_bounds__(64) void k_grad(
    const void* __restrict__ sup, const void* __restrict__ supn,
    const void* __restrict__ normv, const float* __restrict__ REL,
    const int* __restrict__ flag,
    float* __restrict__ RELQ, float* __restrict__ NORMQ)
{
  const int bf = *flag;
  const int b = blockIdx.x, lane = threadIdx.x;
  const int d0 = lane, d1 = lane + 64;
  const bool a1 = (d1 < 100);
  float nv0 = ldf(normv, (size_t)b*100 + d0, bf);
  float nv1 = a1 ? ldf(normv, (size_t)b*100 + d1, bf) : 0.0f;
  float rl0 = REL[(size_t)b*100 + d0];
  float rl1 = a1 ? REL[(size_t)b*100 + d1] : 0.0f;
  float acc0 = 0.0f, acc1 = 0.0f;
  for (int j = 0; j < 5; ++j){
    size_t base = (size_t)(b*5+j)*200;
    float h10 = ldf(sup,  base + d0, bf);
    float t10 = ldf(sup,  base + 100 + d0, bf);
    float h20 = ldf(supn, base + d0, bf);
    float t20 = ldf(supn, base + 100 + d0, bf);
    float h11 = a1 ? ldf(sup,  base + d1, bf) : 0.0f;
    float t11 = a1 ? ldf(sup,  base + 100 + d1, bf) : 0.0f;
    float h21 = a1 ? ldf(supn, base + d1, bf) : 0.0f;
    float t21 = a1 ? ldf(supn, base + 100 + d1, bf) : 0.0f;
    float hd1 = wsum(h10*nv0 + h11*nv1);
    float td1 = wsum(t10*nv0 + t11*nv1);
    float hd2 = wsum(h20*nv0 + h21*nv1);
    float td2 = wsum(t20*nv0 + t21*nv1);
    float upd0 = (h10 - hd1*nv0) + rl0 - (t10 - td1*nv0);
    float upd1 = (h11 - hd1*nv1) + rl1 - (t11 - td1*nv1);
    float und0 = (h20 - hd2*nv0) + rl0 - (t20 - td2*nv0);
    float und1 = (h21 - hd2*nv1) + rl1 - (t21 - td2*nv1);
    if (!a1){ upd1 = 0.0f; und1 = 0.0f; }
    float np2 = wsum(upd0*upd0 + upd1*upd1);
    float nn2 = wsum(und0*und0 + und1*und1);
    float p = -sqrtf(np2), nsc = -sqrtf(nn2);
    if (1.0f - (p - nsc) > 0.0f){
      float ip = 1.0f/sqrtf(np2), in = 1.0f/sqrtf(nn2);
      acc0 += upd0*ip - und0*in;
      acc1 += upd1*ip - und1*in;
    }
  }
  float g0 = acc0 * (1.0f/1280.0f);
  RELQ [(size_t)b*100 + d0] = rl0 - 5.0f*g0;
  NORMQ[(size_t)b*100 + d0] = nv0 - 5.0f*g0;
  if (a1){
    float g1 = acc1 * (1.0f/1280.0f);
    RELQ [(size_t)b*100 + d1] = rl1 - 5.0f*g1;
    NORMQ[(size_t)b*100 + d1] = nv1 - 5.0f*g1;
  }
}

// ---------------------------------------------------------------------------
// Kernel 7: final scores (round-8 verified). h in lanes 0-24, t in 32-56;
// one width-32 butterfly reduces hd AND td simultaneously.
// ---------------------------------------------------------------------------
__global__ __launch_bounds__(256) void k_score(
    const void* __restrict__ query, const void* __restrict__ neg,
    const float* __restrict__ RELQ, const float* __restrict__ NORMQ,
    const int* __restrict__ flag, void* __restrict__ out)
{
  __shared__ __align__(16) float nq[104], rq[104];
  const int bf = *flag;
  const int b = blockIdx.x, tid = threadIdx.x;
  if (tid < 100){ nq[tid] = NORMQ[b*100+tid]; rq[tid] = RELQ[b*100+tid]; }
  __syncthreads();
  const int wid = tid >> 6, lane = tid & 63;
  const bool lo = (lane < 25);
  const bool hi = (lane >= 32 && lane < 57);
  const int d0 = lo ? lane*4 : (hi ? (lane-32)*4 : 0);
  float4 w4 = make_float4(0.0f,0.0f,0.0f,0.0f);
  float4 r4 = make_float4(0.0f,0.0f,0.0f,0.0f);
  if (lo || hi) w4 = *(const float4*)(nq + d0);
  if (lo)       r4 = *(const float4*)(rq + d0);

  for (int qi = blockIdx.y*4 + wid; qi < 522; qi += 32){
    const void* src = (qi < 10) ? query : neg;
    size_t row = (qi < 10) ? ((size_t)b*10 + qi) : ((size_t)b*512 + qi - 10);
    size_t base = row*200 + (hi ? 100 : 0) + d0;
    float4 v = make_float4(0.0f,0.0f,0.0f,0.0f);
    if (lo || hi){
      if (bf){
        uint2 u = *(const uint2*)((const u16*)src + base);
        v.x = u2f(u.x & 0xffffu); v.y = u2f(u.x >> 16);
        v.z = u2f(u.y & 0xffffu); v.w = u2f(u.y >> 16);
      } else {
        v = *(const float4*)((const float*)src + base);
      }
    }
    float pr = v.x*w4.x + v.y*w4.y + v.z*w4.z + v.w*w4.w;
    #pragma unroll
    for (int off = 16; off > 0; off >>= 1) pr += __shfl_xor(pr, off, 32);
    float tdv = __shfl(pr, lane + 32, 64);
    float4 t4;
    t4.x = __shfl(v.x, lane + 32, 64);
    t4.y = __shfl(v.y, lane + 32, 64);
    t4.z = __shfl(v.z, lane + 32, 64);
    t4.w = __shfl(v.w, lane + 32, 64);
    float s2 = 0.0f;
    if (lo){
      float ux = (v.x - pr*w4.x) + r4.x - (t4.x - tdv*w4.x);
      float uy = (v.y - pr*w4.y) + r4.y - (t4.y - tdv*w4.y);
      float uz = (v.z - pr*w4.z) + r4.z - (t4.z - tdv*w4.z);
      float uw = (v.w - pr*w4.w) + r4.w - (t4.w - tdv*w4.w);
      s2 = ux*ux + uy*uy + uz*uz + uw*uw;
    }
    #pragma unroll
    for (int off = 16; off > 0; off >>= 1) s2 += __shfl_xor(s2, off, 32);
    if (lane == 0){
      float sc = -sqrtf(s2);
      size_t oi = (qi < 10) ? ((size_t)b*10 + qi) : (2560 + (size_t)b*512 + (qi - 10));
      if (bf) ((u16*)out)[oi] = f2bu(sc);
      else    ((float*)out)[oi] = sc;
    }
  }
}

// ---------------------------------------------------------------------------
extern "C" void kernel_launch(void* const* d_in, const int* in_sizes, int n_in,
                              void* d_out, int out_size, void* d_ws, size_t ws_size,
                              hipStream_t stream)
{
  const void* support = d_in[0];
  const void* supneg  = d_in[1];
  const void* query   = d_in[2];
  const void* negat   = d_in[3];
  const void* normv   = d_in[4];
  const int* left     = (const int*)d_in[5];
  const int* right    = (const int*)d_in[6];
  const void* emb     = d_in[7];
  const void* gcnw    = d_in[8];
  const void* gcnwb   = d_in[9];
  const void* gcnb    = d_in[10];
  const void* attnw   = d_in[11];
  const void* attnwb  = d_in[12];
  const void* gatew   = d_in[13];
  const void* gatewb  = d_in[14];
  const void* gateb   = d_in[15];
  const void* Wih0    = d_in[16];
  const void* Whh0    = d_in[17];
  const void* bih0    = d_in[18];
  const void* bhh0    = d_in[19];
  const void* Wih1    = d_in[20];
  const void* Whh1    = d_in[21];
  const void* bih1    = d_in[22];
  const void* bhh1    = d_in[23];
  const void* outw    = d_in[24];
  const void* outb    = d_in[25];

  int*   dflag = (int*)d_ws;
  float* fws   = (float*)d_ws + 16;
  // f32 region
  float* Y1   = fws;                 // 5*256*900  = 1,152,000
  float* HF   = Y1 + 1152000;        // 4*256*450  =   460,800
  float* HC   = HF + 460800;         //               460,800 (c in slots 2,3)
  float* CTX  = HC + 460800;         //               460,800
  float* RELb = CTX + 460800;        //    25,600
  float* RELQ = RELb + 25600;        //    25,600
  float* NORMQ= RELQ + 25600;        //    25,600
  float* Bp   = NORMQ + 25600;       //     3,840  (2x1920 permuted bias)
  float* fend = Bp + 3840;           // total f32 = 2,615,040 (16B aligned)
  // u16 region
  u16* Gb   = (u16*)fend;            // 2*1280*1920 = 4,915,200
  u16* X0bf = Gb + 4915200;          // 1280*224    =   286,720
  u16* Y0bf = X0bf + 286720;         // 1280*928    = 1,187,840
  u16* Hbf  = Y0bf + 1187840;        // 2 par * 2*256*480 = 491,520
  u16* Wg   = Hbf + 491520;          // 112*224     =    25,088
  u16* Eb   = Wg + 25088;            // 70001*112   = 7,840,112 (bf16 emb, padded rows)
  // Wp/Whp ALIAS Eb: Eb dead after k_gcn; packs run after (stream-serial).
  u16* Wp   = Eb;                    // 2*1920*928 max = 3,563,520
  u16* Whp  = Eb + 3563520;          // 2*1920*480  = 1,843,200 (sum 5.4M < 7.84M)
  // total ~= 40 MB

  k_detect<<<1, 64, 0, stream>>>((const u32*)normv, dflag);

  // neighbor encoder -> X0bf (self-padding; no memset)
  k_prep<<<(25088 + 70001*28 + 255)/256, 256, 0, stream>>>(gcnw, Wg, emb, Eb, dflag);
  k_gcn<<<2560, 512, 0, stream>>>(left, right, emb, Eb, Wg, gcnwb, gcnb,
                                  attnw, attnwb, gatew, gatewb, gateb,
                                  dflag, X0bf);

  u16* Hpar0 = Hbf;
  u16* Hpar1 = Hbf + 245760;

  // ---- layer 0 ----
  k_packL<<<(2*1920*(224/4) + 2*1920*120 + 3840 + 255)/256, 256, 0, stream>>>(
      Wih0, 200, 224, Wp, Whh0, Whp, bih0, bhh0, Bp, dflag);
  k_mgemm<<<dim3(15,10,2), 256, 0, stream>>>(
      X0bf, 224, 0, Wp, 224, (size_t)1920*224,
      Bp, Gb, 2457600, 1920, 7);
  {
    u16* hc = Hpar0; u16* hn = Hpar1;
    for (int s = 0; s < 5; ++s){
      k_hstep<<<dim3(30,8,2), 64, 0, stream>>>(hc, Whp, Gb, HC, hn,
                                               Y0bf, nullptr, HF, s, 0, s==0);
      u16* tmp = hc; hc = hn; hn = tmp;
    }
  }

  // ---- layer 1 ----
  k_packL<<<(2*1920*(928/4) + 2*1920*120 + 3840 + 255)/256, 256, 0, stream>>>(
      Wih1, 900, 928, Wp, Whh1, Whp, bih1, bhh1, Bp, dflag);
  k_mgemm<<<dim3(15,10,2), 256, 0, stream>>>(
      Y0bf, 928, 0, Wp, 928, (size_t)1920*928,
      Bp, Gb, 2457600, 1920, 29);
  {
    u16* hc = Hpar0; u16* hn = Hpar1;
    for (int s = 0; s < 5; ++s){
      k_hstep<<<dim3(30,8,2), 64, 0, stream>>>(hc, Whp, Gb, HC, hn,
                                               nullptr, Y1, HF, s, 1, s==0);
      u16* tmp = hc; hc = hn; hn = tmp;
    }
  }

  k_attn<<<256, 256, 0, stream>>>(Y1, HF, CTX);
  k_gemm<<<dim3(1,256), 256, 1800*4, stream>>>(CTX, outw, 0, outb, nullptr, 0,
                                               dflag, RELb, 1800, 100);
  k_grad<<<256, 64, 0, stream>>>(support, supneg, normv, RELb, dflag, RELQ, NORMQ);
  k_score<<<dim3(256,8), 256, 0, stream>>>(query, negat, RELQ, NORMQ, dflag, d_out);
}

// Round 13
// 588.103 us; speedup vs baseline: 1.1527x; 1.1527x over previous
//
#include <hip/hip_runtime.h>

typedef unsigned short u16;
typedef unsigned int   u32;
typedef __attribute__((ext_vector_type(8))) short short8;
typedef __attribute__((ext_vector_type(4))) float f32x4;

__device__ __forceinline__ float u2f(u32 u){
  union { u32 i; float f; } v; v.i = u << 16; return v.f;
}
__device__ __forceinline__ u16 f2bu(float f){
  union { float f; u32 i; } v; v.f = f;
  u32 i = v.i;
  i += 0x7fffu + ((i >> 16) & 1u);   // round-to-nearest-even
  return (u16)(i >> 16);
}
__device__ __forceinline__ float sigm(float x){ return 1.0f/(1.0f + expf(-x)); }
__device__ __forceinline__ float ldf(const void* p, size_t i, int bf){
  return bf ? u2f(((const u16*)p)[i]) : ((const float*)p)[i];
}
__device__ __forceinline__ float wsum(float v){
  #pragma unroll
  for (int off = 32; off > 0; off >>= 1) v += __shfl_xor(v, off, 64);
  return v;
}

// ---------------------------------------------------------------------------
// Kernel 0: dtype detector (bf16 vs f32 device buffers).
// ---------------------------------------------------------------------------
__global__ __launch_bounds__(64) void k_detect(const u32* __restrict__ nv,
                                               int* __restrict__ flag)
{
  int i = threadIdx.x;
  u32 w = nv[i];
  u32 e = (w >> 7) & 0xffu;
  bool sane = (e >= 100u && e <= 140u);
  unsigned long long m = __ballot(sane);
  if (i == 0) *flag = (__popcll(m) >= 40) ? 1 : 0;
}

// ---------------------------------------------------------------------------
// Kernel PR: merged prep — gcn_w pack (Wg [112][224]) + emb->bf16 (Eb).
// Range 0..25087: Wg; 25088..: Eb in 4-elem units (1,750,025 units).
// ---------------------------------------------------------------------------
__global__ __launch_bounds__(256) void k_prep(
    const void* __restrict__ gcnw, u16* __restrict__ Wg,
    const void* __restrict__ emb, u16* __restrict__ Eb,
    const int* __restrict__ flag)
{
  const int bf = *flag;
  int idx = blockIdx.x*256 + threadIdx.x;
  if (idx < 25088){
    int r = idx / 224, k = idx - r*224;
    u16 v = 0;
    if (k < 200 && r < 100){
      size_t si = (size_t)r*200 + k;
      v = bf ? ((const u16*)gcnw)[si] : f2bu(((const float*)gcnw)[si]);
    }
    Wg[idx] = v;
    return;
  }
  int e4 = idx - 25088;
  if (e4 >= 1750025) return;
  size_t i = (size_t)e4*4;
  union { u16 q[4]; uint2 d; } o;
  if (bf){
    o.d = *(const uint2*)((const u16*)emb + i);
  } else {
    float4 t = *(const float4*)((const float*)emb + i);
    o.q[0] = f2bu(t.x); o.q[1] = f2bu(t.y);
    o.q[2] = f2bu(t.z); o.q[3] = f2bu(t.w);
  }
  *(uint2*)(Eb + i) = o.d;
}

// ---------------------------------------------------------------------------
// helpers for the merged layer pack
// ---------------------------------------------------------------------------
__device__ __forceinline__ void packg_one(
    const void* __restrict__ src, u16* __restrict__ dst,
    int K, int Kp, int bf, int idx)   // idx in 4-elem units over 2*1920*Kp/4
{
  const int Kq = Kp >> 2;
  const int per = 1920*Kq;
  int z = idx / per, r = idx - z*per;
  int rp = r / Kq, cq = r - rp*Kq;
  int c0 = cq*4;
  int kblk = rp >> 6, rem = rp & 63, gate = rem >> 4, klo = rem & 15;
  int k = kblk*16 + klo;
  union { u16 q[4]; uint2 d; } o;
  o.q[0] = 0; o.q[1] = 0; o.q[2] = 0; o.q[3] = 0;
  if (k < 450){
    size_t base = ((size_t)z*1800 + (size_t)gate*450 + k)*K;
    #pragma unroll
    for (int e = 0; e < 4; ++e){
      int c = c0 + e;
      if (c < K)
        o.q[e] = bf ? ((const u16*)src)[base+c] : f2bu(((const float*)src)[base+c]);
    }
  }
  *(uint2*)(dst + (size_t)idx*4) = o.d;
}

// ---------------------------------------------------------------------------
// Kernel PL: merged per-layer pack: Wih->Wp (gate-interleaved), Whh->Whp,
// bias->Bp. Flat ranges: [0,n1) Wp units, [n1,n1+n2) Whp units, then Bp.
// ---------------------------------------------------------------------------
__global__ __launch_bounds__(256) void k_packL(
    const void* __restrict__ Wih, int Kih, int KpIh, u16* __restrict__ Wp,
    const void* __restrict__ Whh, u16* __restrict__ Whp,
    const void* __restrict__ bih, const void* __restrict__ bhh,
    float* __restrict__ Bp, const int* __restrict__ flag)
{
  const int bf = *flag;
  const int n1 = 2*1920*(KpIh >> 2);
  const int n2 = 2*1920*120;            // Whh: Kp=480 -> 120 units
  int idx = blockIdx.x*256 + threadIdx.x;
  if (idx < n1){ packg_one(Wih, Wp, Kih, KpIh, bf, idx); return; }
  idx -= n1;
  if (idx < n2){ packg_one(Whh, Whp, 450, 480, bf, idx); return; }
  idx -= n2;
  if (idx >= 2*1920) return;
  int z = idx / 1920, rp = idx - z*1920;
  int kblk = rp >> 6, rem = rp & 63, gate = rem >> 4, klo = rem & 15;
  int k = kblk*16 + klo;
  float v = 0.0f;
  if (k < 450){
    size_t si = (size_t)z*1800 + (size_t)gate*450 + k;
    v = ldf(bih, si, bf) + ldf(bhh, si, bf);
  }
  Bp[idx] = v;
}

// ---------------------------------------------------------------------------
// Kernel 1: neighbor encoder (round-11 verified, 644us build). Gathers read
// pre-packed bf16 emb (Eb, stride 100); register prefetch; shfl tail;
// self-padding X0bf.
// ---------------------------------------------------------------------------
__global__ __launch_bounds__(512, 4) void k_gcn(
    const int* __restrict__ left, const int* __restrict__ right,
    const void* __restrict__ emb, const u16* __restrict__ Eb,
    const u16* __restrict__ Wg,
    const void* __restrict__ gcnwb, const void* __restrict__ gcnb,
    const void* __restrict__ attnw, const void* __restrict__ attnwb,
    const void* __restrict__ gatew, const void* __restrict__ gatewb,
    const void* __restrict__ gateb,
    const int* __restrict__ flag,
    u16* __restrict__ X0bf)
{
  __shared__ __align__(16) u16 As[208*40];    // 16640 B
  __shared__ __align__(16) u16 Bs[112*232];   // 51968 B
  __shared__ int c1_s[200], c2_s[200];
  __shared__ float logit_s[208];
  __shared__ float red_s[512];
  __shared__ float attnw_s[112], bias_s[112], gatew_s[112], oa_s[112];

  const int bf  = *flag;
  const int tid = threadIdx.x;
  const int n   = blockIdx.x;
  const int b   = n & 255;
  const int fs  = n >> 8;
  const int s   = fs & 1;
  const int f   = fs >> 1;
  const int* conn = (s == 0 ? left : right) + (size_t)(f*256 + b)*600;

  if (tid < 200){ c1_s[tid] = conn[tid*3+1]; c2_s[tid] = conn[tid*3+2]; }
  if (tid < 112){
    attnw_s[tid] = (tid < 100) ? ldf(attnw, tid, bf) : 0.0f;
    bias_s[tid]  = (tid < 100) ? (ldf(gcnwb, tid, bf) + ldf(gcnb, tid, bf)) : 0.0f;
    gatew_s[tid] = (tid < 100) ? ldf(gatew, tid, bf) : 0.0f;
    oa_s[tid] = 0.0f;
  }
  for (int g = tid; g < 112*28; g += 512){
    int r = g / 28, cc = g - r*28;
    *(short8*)(Bs + r*232 + cc*8) = *(const short8*)(Wg + (size_t)r*224 + cc*8);
  }
  // pad cols 200..223 of this row (done by the s==1 block)
  if (s == 1 && tid >= 100 && tid < 124)
    X0bf[((size_t)f*256 + b)*224 + 100 + tid] = 0;
  __syncthreads();

  const int wid  = tid >> 6, lane = tid & 63, ln = lane & 15, quad = lane >> 4;
  const int mt0 = (wid < 5) ? 2*wid : (10 + (wid - 5));
  const int nmt = (wid < 5) ? 2 : 1;

  // gather kc's A-slots (bf16 table, 8 B/slot) into registers
  auto loadA = [&](int kc, uint2* pv){
    #pragma unroll
    for (int it = 0; it < 4; ++it){
      int g = tid + it*512;
      uint2 v; v.x = 0u; v.y = 0u;
      if (g < 1664){
        int r = g >> 3, gi = g & 7, k = kc*32 + gi*4;
        if (r < 200 && k < 200){
          int c  = (k < 100) ? c1_s[r] : c2_s[r];
          int kk = (k < 100) ? k : (k - 100);
          v = *(const uint2*)(Eb + (size_t)c*100 + kk);
        }
      }
      pv[it] = v;
    }
  };

  f32x4 acc[2][7];
  #pragma unroll
  for (int i = 0; i < 2; ++i)
    #pragma unroll
    for (int j = 0; j < 7; ++j) acc[i][j] = (f32x4)0.0f;

  uint2 pv[4];
  loadA(0, pv);

  for (int kc = 0; kc < 7; ++kc){
    const int k0 = kc*32;
    #pragma unroll
    for (int it = 0; it < 4; ++it){
      int g = tid + it*512;
      if (g < 1664){
        int r = g >> 3, gi = g & 7;
        *(uint2*)(As + r*40 + gi*4) = pv[it];
      }
    }
    __syncthreads();
    if (kc < 6) loadA(kc+1, pv);   // in flight under MFMA phase

    #pragma unroll
    for (int mi = 0; mi < 2; ++mi){
      if (mi < nmt){
        short8 afr = *(const short8*)(As + ((mt0+mi)*16 + ln)*40 + quad*8);
        #pragma unroll
        for (int nt = 0; nt < 7; ++nt){
          short8 bfr = *(const short8*)(Bs + (size_t)(nt*16 + ln)*232 + k0 + quad*8);
          acc[mi][nt] = __builtin_amdgcn_mfma_f32_16x16x32_bf16(afr, bfr, acc[mi][nt], 0, 0, 0);
        }
      }
    }
    __syncthreads();
  }

  const float awb = ldf(attnwb, 0, bf);
  #pragma unroll
  for (int mi = 0; mi < 2; ++mi){
    if (mi < nmt){
      #pragma unroll
      for (int rg = 0; rg < 4; ++rg){
        float p = 0.0f;
        #pragma unroll
        for (int nt = 0; nt < 7; ++nt){
          float x = acc[mi][nt][rg] + bias_s[nt*16 + ln];
          x = x > 0.0f ? x : 0.01f*x;
          p += x * attnw_s[nt*16 + ln];
        }
        p += __shfl_xor(p, 1, 64); p += __shfl_xor(p, 2, 64);
        p += __shfl_xor(p, 4, 64); p += __shfl_xor(p, 8, 64);
        int m = (mt0+mi)*16 + quad*4 + rg;
        if (ln == 0 && m < 200) logit_s[m] = p + awb;
      }
    }
  }
  __syncthreads();

  red_s[tid] = (tid < 200) ? logit_s[tid] : -3.0e38f;
  __syncthreads();
  for (int off = 256; off > 0; off >>= 1){
    if (tid < off) red_s[tid] = fmaxf(red_s[tid], red_s[tid+off]);
    __syncthreads();
  }
  float mx = red_s[0];
  __syncthreads();
  float ev = 0.0f;
  if (tid < 200) ev = expf(logit_s[tid] - mx);
  red_s[tid] = ev;
  __syncthreads();
  for (int off = 256; off > 0; off >>= 1){
    if (tid < off) red_s[tid] += red_s[tid+off];
    __syncthreads();
  }
  float S = red_s[0];
  __syncthreads();
  if (tid < 208) logit_s[tid] = (tid < 200) ? ev*(1.0f/S) : 0.0f;
  __syncthreads();

  float at[2][4];
  #pragma unroll
  for (int mi = 0; mi < 2; ++mi)
    #pragma unroll
    for (int rg = 0; rg < 4; ++rg)
      at[mi][rg] = (mi < nmt) ? logit_s[(mt0+mi)*16 + quad*4 + rg] : 0.0f;

  #pragma unroll
  for (int nt = 0; nt < 7; ++nt){
    float p = 0.0f;
    #pragma unroll
    for (int mi = 0; mi < 2; ++mi){
      if (mi < nmt){
        #pragma unroll
        for (int rg = 0; rg < 4; ++rg){
          float x = acc[mi][nt][rg] + bias_s[nt*16 + ln];
          x = x > 0.0f ? x : 0.01f*x;
          p += x * at[mi][rg];
        }
      }
    }
    p += __shfl_xor(p, 16, 64); p += __shfl_xor(p, 32, 64);
    if (quad == 0) atomicAdd(&oa_s[nt*16 + ln], p);
  }
  __syncthreads();

  red_s[tid] = (tid < 100) ? oa_s[tid]*gatew_s[tid] : 0.0f;
  __syncthreads();
  for (int off = 256; off > 0; off >>= 1){
    if (tid < off) red_s[tid] += red_s[tid+off];
    __syncthreads();
  }
  float gate = sigm(red_s[0] + ldf(gatewb, 0, bf) + ldf(gateb, 0, bf));
  if (tid < 100){
    int c0 = conn[0];
    float self = ldf(emb, (size_t)c0*100 + tid, bf);
    X0bf[((size_t)f*256 + b)*224 + s*100 + tid] = f2bu(oa_s[tid]*gate + self*(1.0f - gate));
  }
}

// ---------------------------------------------------------------------------
// Kernel M: MFMA GEMM (input projections only). out[z][row][col'] bf16 =
// A[row]·B'[col'] + Bp[z][col']. N=1920 exact (15x128 tiles), M mult of 128.
// ---------------------------------------------------------------------------
__global__ __launch_bounds__(256) void k_mgemm(
    const u16* __restrict__ A, int lda, size_t Astride,
    const u16* __restrict__ B, int ldb, size_t Bstride,
    const float* __restrict__ bsum,
    u16* __restrict__ out, size_t Ostride,
    int N, int KC)
{
  __shared__ __align__(16) u16 As[128*40];
  __shared__ __align__(16) u16 Bs[128*40];
  const int tid = threadIdx.x;
  const int z  = blockIdx.z;
  const int nb = blockIdx.x, mb = blockIdx.y;
  const u16* Az = A + (size_t)z*Astride;
  const u16* Bz = B + (size_t)z*Bstride;

  const int wid = tid >> 6, lane = tid & 63, ln = lane & 15, quad = lane >> 4;
  const int wm = wid >> 1, wn = wid & 1;

  f32x4 acc[4][4];
  #pragma unroll
  for (int i = 0; i < 4; ++i)
    #pragma unroll
    for (int j = 0; j < 4; ++j) acc[i][j] = (f32x4)0.0f;

  const int srow = tid >> 1;
  const int koff = (tid & 1)*16;
  const int rowA = mb*128 + srow;
  const int rowB = nb*128 + srow;

  for (int kc = 0; kc < KC; ++kc){
    const int k0 = kc*32 + koff;
    const u16* ap = Az + (size_t)rowA*lda + k0;
    const u16* bp = Bz + (size_t)rowB*ldb + k0;
    short8 av0 = *(const short8*)(ap);
    short8 av1 = *(const short8*)(ap + 8);
    short8 bv0 = *(const short8*)(bp);
    short8 bv1 = *(const short8*)(bp + 8);
    *(short8*)(As + srow*40 + koff)     = av0;
    *(short8*)(As + srow*40 + koff + 8) = av1;
    *(short8*)(Bs + srow*40 + koff)     = bv0;
    *(short8*)(Bs + srow*40 + koff + 8) = bv1;
    __syncthreads();
    short8 af[4], bfr[4];
    #pragma unroll
    for (int i = 0; i < 4; ++i)
      af[i] = *(const short8*)(As + (wm*64 + i*16 + ln)*40 + quad*8);
    #pragma unroll
    for (int j = 0; j < 4; ++j)
      bfr[j] = *(const short8*)(Bs + (wn*64 + j*16 + ln)*40 + quad*8);
    #pragma unroll
    for (int i = 0; i < 4; ++i)
      #pragma unroll
      for (int j = 0; j < 4; ++j)
        acc[i][j] = __builtin_amdgcn_mfma_f32_16x16x32_bf16(af[i], bfr[j], acc[i][j], 0, 0, 0);
    __syncthreads();
  }

  #pragma unroll
  for (int j = 0; j < 4; ++j){
    int col = nb*128 + wn*64 + j*16 + ln;
    float bias = bsum ? bsum[(size_t)z*1920 + col] : 0.0f;
    #pragma unroll
    for (int i = 0; i < 4; ++i){
      #pragma unroll
      for (int rg = 0; rg < 4; ++rg){
        int row = mb*128 + wm*64 + i*16 + quad*4 + rg;
        out[(size_t)z*Ostride + (size_t)row*N + col] = f2bu(acc[i][j][rg] + bias);
      }
    }
  }
}

// ---------------------------------------------------------------------------
// Kernel H: fused hidden GEMM + LSTM cell, BARRIER-FREE / ZERO-LDS
// (round-11 verified, 960 one-wave blocks, 16 rows x 64 cols' per wave).
// `first` flag: s==0 skips the K-loop and c-read. Self-zeroing pads.
// ---------------------------------------------------------------------------
__global__ __launch_bounds__(64) void k_hstep(
    const u16* __restrict__ Hin, const u16* __restrict__ Whp,
    const u16* __restrict__ Gb, float* __restrict__ HC,
    u16* __restrict__ Hout, u16* __restrict__ Ybf, float* __restrict__ Yf,
    float* __restrict__ HF, int s, int layer, int first)
{
  const int lane = threadIdx.x;
  const int ln = lane & 15, quad = lane >> 4;
  const int kb = blockIdx.x;      // 0..29: 64-col' group
  const int mb = blockIdx.y;      // 0..15: 16-row group
  const int z  = blockIdx.z;

  f32x4 acc[4];
  #pragma unroll
  for (int j = 0; j < 4; ++j) acc[j] = (f32x4)0.0f;

  if (!first){
    const u16* Az = Hin + ((size_t)z*256 + mb*16)*480;
    const u16* Bz = Whp + (size_t)z*1920*480 + (size_t)kb*64*480;
    #pragma unroll
    for (int kc = 0; kc < 15; ++kc){
      const int k0 = kc*32 + quad*8;
      short8 afr = *(const short8*)(Az + (size_t)ln*480 + k0);
      #pragma unroll
      for (int j = 0; j < 4; ++j){
        short8 bfr = *(const short8*)(Bz + (size_t)(j*16 + ln)*480 + k0);
        acc[j] = __builtin_amdgcn_mfma_f32_16x16x32_bf16(afr, bfr, acc[j], 0, 0, 0);
      }
    }
  }

  const int k = kb*16 + ln;
  const int t = z ? (4 - s) : s;
  if (k < 450){
    const u16* Gz = Gb + (size_t)z*2457600 + (size_t)t*256*1920;
    #pragma unroll
    for (int rg = 0; rg < 4; ++rg){
      int b = mb*16 + quad*4 + rg;
      const u16* grow = Gz + (size_t)b*1920 + kb*64 + ln;
      float gi = acc[0][rg] + u2f(grow[0]);
      float gf = acc[1][rg] + u2f(grow[16]);
      float gg = acc[2][rg] + u2f(grow[32]);
      float go = acc[3][rg] + u2f(grow[48]);
      float* cp = HC + ((size_t)(2+z)*256 + b)*450 + k;
      float cprv = first ? 0.0f : *cp;
      float c = sigm(gf)*cprv + sigm(gi)*tanhf(gg);
      float h = sigm(go)*tanhf(c);
      *cp = c;
      Hout[((size_t)z*256 + b)*480 + k] = f2bu(h);
      if (Ybf) Ybf[((size_t)t*256 + b)*928 + z*450 + k] = f2bu(h);
      else     Yf [((size_t)t*256 + b)*900 + z*450 + k] = h;
      HF[((size_t)(layer*2+z)*256 + b)*450 + k] = h;
    }
  } else {
    // pad maintenance: Hout cols [450,480); Y0bf cols [900,928) (z==1 only)
    #pragma unroll
    for (int rg = 0; rg < 4; ++rg){
      int b = mb*16 + quad*4 + rg;
      Hout[((size_t)z*256 + b)*480 + k] = 0;
      if (z == 1 && Ybf && k < 478)
        Ybf[((size_t)t*256 + b)*928 + 450 + k] = 0;
    }
  }
}

// ---------------------------------------------------------------------------
// Kernel T: fused tail = attention + context + (CTX @ out_w + outb) + meta-
// gradient. One block per b; CTX lives in LDS (never hits global); REL goes
// through LDS into the wave-0 grad phase. Writes RELQ/NORMQ for k_score.
// ---------------------------------------------------------------------------
__global__ __launch_bounds__(256) void k_tail(
    const float* __restrict__ Y1, const float* __restrict__ HF,
    const void* __restrict__ outw, const void* __restrict__ outb,
    const void* __restrict__ sup, const void* __restrict__ supn,
    const void* __restrict__ normv,
    const int* __restrict__ flag,
    float* __restrict__ RELQ, float* __restrict__ NORMQ)
{
  __shared__ float red2[40];
  __shared__ float aw[10];
  __shared__ __align__(16) float ctx[1800];
  __shared__ float rel_s[104];
  const int bf = *flag;
  const int b = blockIdx.x, tid = threadIdx.x;
  const int wid = tid >> 6, lane = tid & 63;

  // ---- attention scores over (t,l) ----
  for (int p = 0; p < 10; ++p){
    int t = p >> 1, l = p & 1;
    float a = 0.0f;
    for (int h = tid; h < 900; h += 256)
      a += Y1[((size_t)t*256 + b)*900 + h] * HF[(size_t)b*1800 + h*2 + l];
    a = wsum(a);
    if (lane == 0) red2[p*4 + wid] = a;
  }
  __syncthreads();
  if (tid < 2){
    int l = tid;
    float sc[5];
    float mxv = -3.0e38f;
    for (int t = 0; t < 5; ++t){
      int p = t*2 + l;
      sc[t] = red2[p*4] + red2[p*4+1] + red2[p*4+2] + red2[p*4+3];
      mxv = fmaxf(mxv, sc[t]);
    }
    float e[5], sum = 0.0f;
    for (int t = 0; t < 5; ++t){ e[t] = expf(sc[t]-mxv); sum += e[t]; }
    for (int t = 0; t < 5; ++t) aw[t*2+l] = e[t]/sum;
  }
  __syncthreads();
  // ---- context -> LDS (hidden layout: ctx[h*2+l]) ----
  for (int h = tid; h < 900; h += 256){
    float v0 = 0.0f, v1 = 0.0f;
    for (int t = 0; t < 5; ++t){
      float y = Y1[((size_t)t*256 + b)*900 + h];
      v0 += y*aw[t*2+0]; v1 += y*aw[t*2+1];
    }
    ctx[h*2+0] = v0;
    ctx[h*2+1] = v1;
  }
  __syncthreads();
  // ---- REL[j] = ctx . out_w[j] + outb[j] ----
  if (tid < 100){
    float acc = ldf(outb, tid, bf);
    if (bf){
      const u16* w = (const u16*)outw + (size_t)tid*1800;
      for (int k = 0; k < 1800; k += 4){
        uint2 wv = *(const uint2*)(w + k);
        acc += ctx[k]   * u2f(wv.x & 0xffffu);
        acc += ctx[k+1] * u2f(wv.x >> 16);
        acc += ctx[k+2] * u2f(wv.y & 0xffffu);
        acc += ctx[k+3] * u2f(wv.y >> 16);
      }
    } else {
      const float* w = (const float*)outw + (size_t)tid*1800;
      for (int k = 0; k < 1800; k += 4){
        float4 wv = *(const float4*)(w + k);
        acc += ctx[k]*wv.x + ctx[k+1]*wv.y + ctx[k+2]*wv.z + ctx[k+3]*wv.w;
      }
    }
    rel_s[tid] = acc;
  }
  __syncthreads();
  // ---- meta-gradient (wave 0 only; lane owns dims {lane, lane+64}) ----
  if (wid == 0){
    const int d0 = lane, d1 = lane + 64;
    const bool a1 = (d1 < 100);
    float nv0 = ldf(normv, (size_t)b*100 + d0, bf);
    float nv1 = a1 ? ldf(normv, (size_t)b*100 + d1, bf) : 0.0f;
    float rl0 = rel_s[d0];
    float rl1 = a1 ? rel_s[d1] : 0.0f;
    float acc0 = 0.0f, acc1 = 0.0f;
    for (int j = 0; j < 5; ++j){
      size_t base = (size_t)(b*5+j)*200;
      float h10 = ldf(sup,  base + d0, bf);
      float t10 = ldf(sup,  base + 100 + d0, bf);
      float h20 = ldf(supn, base + d0, bf);
      float t20 = ldf(supn, base + 100 + d0, bf);
      float h11 = a1 ? ldf(sup,  base + d1, bf) : 0.0f;
      float t11 = a1 ? ldf(sup,  base + 100 + d1, bf) : 0.0f;
      float h21 = a1 ? ldf(supn, base + d1, bf) : 0.0f;
      float t21 = a1 ? ldf(supn, base + 100 + d1, bf) : 0.0f;
      float hd1 = wsum(h10*nv0 + h11*nv1);
      float td1 = wsum(t10*nv0 + t11*nv1);
      float hd2 = wsum(h20*nv0 + h21*nv1);
      float td2 = wsum(t20*nv0 + t21*nv1);
      float upd0 = (h10 - hd1*nv0) + rl0 - (t10 - td1*nv0);
      float upd1 = (h11 - hd1*nv1) + rl1 - (t11 - td1*nv1);
      float und0 = (h20 - hd2*nv0) + rl0 - (t20 - td2*nv0);
      float und1 = (h21 - hd2*nv1) + rl1 - (t21 - td2*nv1);
      if (!a1){ upd1 = 0.0f; und1 = 0.0f; }
      float np2 = wsum(upd0*upd0 + upd1*upd1);
      float nn2 = wsum(und0*und0 + und1*und1);
      float p = -sqrtf(np2), nsc = -sqrtf(nn2);
      if (1.0f - (p - nsc) > 0.0f){
        float ip = 1.0f/sqrtf(np2), in = 1.0f/sqrtf(nn2);
        acc0 += upd0*ip - und0*in;
        acc1 += upd1*ip - und1*in;
      }
    }
    float g0 = acc0 * (1.0f/1280.0f);
    RELQ [(size_t)b*100 + d0] = rl0 - 5.0f*g0;
    NORMQ[(size_t)b*100 + d0] = nv0 - 5.0f*g0;
    if (a1){
      float g1 = acc1 * (1.0f/1280.0f);
      RELQ [(size_t)b*100 + d1] = rl1 - 5.0f*g1;
      NORMQ[(size_t)b*100 + d1] = nv1 - 5.0f*g1;
    }
  }
}

// ---------------------------------------------------------------------------
// Kernel 7: final scores (round-8 verified). h in lanes 0-24, t in 32-56;
// one width-32 butterfly reduces hd AND td simultaneously.
// ---------------------------------------------------------------------------
__global__ __launch_bounds__(256) void k_score(
    const void* __restrict__ query, const void* __restrict__ neg,
    const float* __restrict__ RELQ, const float* __restrict__ NORMQ,
    const int* __restrict__ flag, void* __restrict__ out)
{
  __shared__ __align__(16) float nq[104], rq[104];
  const int bf = *flag;
  const int b = blockIdx.x, tid = threadIdx.x;
  if (tid < 100){ nq[tid] = NORMQ[b*100+tid]; rq[tid] = RELQ[b*100+tid]; }
  __syncthreads();
  const int wid = tid >> 6, lane = tid & 63;
  const bool lo = (lane < 25);
  const bool hi = (lane >= 32 && lane < 57);
  const int d0 = lo ? lane*4 : (hi ? (lane-32)*4 : 0);
  float4 w4 = make_float4(0.0f,0.0f,0.0f,0.0f);
  float4 r4 = make_float4(0.0f,0.0f,0.0f,0.0f);
  if (lo || hi) w4 = *(const float4*)(nq + d0);
  if (lo)       r4 = *(const float4*)(rq + d0);

  for (int qi = blockIdx.y*4 + wid; qi < 522; qi += 32){
    const void* src = (qi < 10) ? query : neg;
    size_t row = (qi < 10) ? ((size_t)b*10 + qi) : ((size_t)b*512 + qi - 10);
    size_t base = row*200 + (hi ? 100 : 0) + d0;
    float4 v = make_float4(0.0f,0.0f,0.0f,0.0f);
    if (lo || hi){
      if (bf){
        uint2 u = *(const uint2*)((const u16*)src + base);
        v.x = u2f(u.x & 0xffffu); v.y = u2f(u.x >> 16);
        v.z = u2f(u.y & 0xffffu); v.w = u2f(u.y >> 16);
      } else {
        v = *(const float4*)((const float*)src + base);
      }
    }
    float pr = v.x*w4.x + v.y*w4.y + v.z*w4.z + v.w*w4.w;
    #pragma unroll
    for (int off = 16; off > 0; off >>= 1) pr += __shfl_xor(pr, off, 32);
    float tdv = __shfl(pr, lane + 32, 64);
    float4 t4;
    t4.x = __shfl(v.x, lane + 32, 64);
    t4.y = __shfl(v.y, lane + 32, 64);
    t4.z = __shfl(v.z, lane + 32, 64);
    t4.w = __shfl(v.w, lane + 32, 64);
    float s2 = 0.0f;
    if (lo){
      float ux = (v.x - pr*w4.x) + r4.x - (t4.x - tdv*w4.x);
      float uy = (v.y - pr*w4.y) + r4.y - (t4.y - tdv*w4.y);
      float uz = (v.z - pr*w4.z) + r4.z - (t4.z - tdv*w4.z);
      float uw = (v.w - pr*w4.w) + r4.w - (t4.w - tdv*w4.w);
      s2 = ux*ux + uy*uy + uz*uz + uw*uw;
    }
    #pragma unroll
    for (int off = 16; off > 0; off >>= 1) s2 += __shfl_xor(s2, off, 32);
    if (lane == 0){
      float sc = -sqrtf(s2);
      size_t oi = (qi < 10) ? ((size_t)b*10 + qi) : (2560 + (size_t)b*512 + (qi - 10));
      if (bf) ((u16*)out)[oi] = f2bu(sc);
      else    ((float*)out)[oi] = sc;
    }
  }
}

// ---------------------------------------------------------------------------
extern "C" void kernel_launch(void* const* d_in, const int* in_sizes, int n_in,
                              void* d_out, int out_size, void* d_ws, size_t ws_size,
                              hipStream_t stream)
{
  const void* support = d_in[0];
  const void* supneg  = d_in[1];
  const void* query   = d_in[2];
  const void* negat   = d_in[3];
  const void* normv   = d_in[4];
  const int* left     = (const int*)d_in[5];
  const int* right    = (const int*)d_in[6];
  const void* emb     = d_in[7];
  const void* gcnw    = d_in[8];
  const void* gcnwb   = d_in[9];
  const void* gcnb    = d_in[10];
  const void* attnw   = d_in[11];
  const void* attnwb  = d_in[12];
  const void* gatew   = d_in[13];
  const void* gatewb  = d_in[14];
  const void* gateb   = d_in[15];
  const void* Wih0    = d_in[16];
  const void* Whh0    = d_in[17];
  const void* bih0    = d_in[18];
  const void* bhh0    = d_in[19];
  const void* Wih1    = d_in[20];
  const void* Whh1    = d_in[21];
  const void* bih1    = d_in[22];
  const void* bhh1    = d_in[23];
  const void* outw    = d_in[24];
  const void* outb    = d_in[25];

  int*   dflag = (int*)d_ws;
  float* fws   = (float*)d_ws + 16;
  // f32 region
  float* Y1   = fws;                 // 5*256*900  = 1,152,000
  float* HF   = Y1 + 1152000;        // 4*256*450  =   460,800
  float* HC   = HF + 460800;         //               460,800 (c in slots 2,3)
  float* CTX  = HC + 460800;         //               460,800 (unused, kept)
  float* RELb = CTX + 460800;        //    25,600 (unused, kept)
  float* RELQ = RELb + 25600;        //    25,600
  float* NORMQ= RELQ + 25600;        //    25,600
  float* Bp   = NORMQ + 25600;       //     3,840  (2x1920 permuted bias)
  float* fend = Bp + 3840;           // total f32 = 2,615,040 (16B aligned)
  // u16 region
  u16* Gb   = (u16*)fend;            // 2*1280*1920 = 4,915,200
  u16* X0bf = Gb + 4915200;          // 1280*224    =   286,720
  u16* Y0bf = X0bf + 286720;         // 1280*928    = 1,187,840
  u16* Hbf  = Y0bf + 1187840;        // 2 par * 2*256*480 = 491,520
  u16* Wg   = Hbf + 491520;          // 112*224     =    25,088
  u16* Eb   = Wg + 25088;            // 70001*100   = 7,000,100 (bf16 emb)
  // Wp/Whp ALIAS Eb: Eb dead after k_gcn; packs run after (stream-serial).
  u16* Wp   = Eb;                    // 2*1920*928 max = 3,563,520
  u16* Whp  = Eb + 3563520;          // 2*1920*480  = 1,843,200 (sum 5.4M < 7.0M)
  // total ~= 38.3 MB

  k_detect<<<1, 64, 0, stream>>>((const u32*)normv, dflag);

  // neighbor encoder -> X0bf (self-padding; no memset)
  k_prep<<<(25088+1750025+255)/256, 256, 0, stream>>>(gcnw, Wg, emb, Eb, dflag);
  k_gcn<<<2560, 512, 0, stream>>>(left, right, emb, Eb, Wg, gcnwb, gcnb,
                                  attnw, attnwb, gatew, gatewb, gateb,
                                  dflag, X0bf);

  u16* Hpar0 = Hbf;
  u16* Hpar1 = Hbf + 245760;

  // ---- layer 0 ----
  k_packL<<<(2*1920*(224/4) + 2*1920*120 + 3840 + 255)/256, 256, 0, stream>>>(
      Wih0, 200, 224, Wp, Whh0, Whp, bih0, bhh0, Bp, dflag);
  k_mgemm<<<dim3(15,10,2), 256, 0, stream>>>(
      X0bf, 224, 0, Wp, 224, (size_t)1920*224,
      Bp, Gb, 2457600, 1920, 7);
  {
    u16* hc = Hpar0; u16* hn = Hpar1;
    for (int s = 0; s < 5; ++s){
      k_hstep<<<dim3(30,16,2), 64, 0, stream>>>(hc, Whp, Gb, HC, hn,
                                                Y0bf, nullptr, HF, s, 0, s==0);
      u16* tmp = hc; hc = hn; hn = tmp;
    }
  }

  // ---- layer 1 ----
  k_packL<<<(2*1920*(928/4) + 2*1920*120 + 3840 + 255)/256, 256, 0, stream>>>(
      Wih1, 900, 928, Wp, Whh1, Whp, bih1, bhh1, Bp, dflag);
  k_mgemm<<<dim3(15,10,2), 256, 0, stream>>>(
      Y0bf, 928, 0, Wp, 928, (size_t)1920*928,
      Bp, Gb, 2457600, 1920, 29);
  {
    u16* hc = Hpar0; u16* hn = Hpar1;
    for (int s = 0; s < 5; ++s){
      k_hstep<<<dim3(30,16,2), 64, 0, stream>>>(hc, Whp, Gb, HC, hn,
                                                nullptr, Y1, HF, s, 1, s==0);
      u16* tmp = hc; hc = hn; hn = tmp;
    }
  }

  k_tail<<<256, 256, 0, stream>>>(Y1, HF, outw, outb, support, supneg, normv,
                                  dflag, RELQ, NORMQ);
  k_score<<<dim3(256,8), 256, 0, stream>>>(query, negat, RELQ, NORMQ, dflag, d_out);
}